// Round 3
// baseline (19.096 us; speedup 1.0000x reference)
//
#include <hip/hip_runtime.h>

// Problem constants: bs=2, V=4096, N=32, S=8, K=64 (S*K=512)
#define BS 2
#define V_DIM 4096
#define N_NBR 32
#define S_SUP 8
#define K_OUT 64
#define SK (S_SUP * K_OUT)
#define EPS 1e-12f

#define BLOCK_THREADS 1024
#define WAVES_PER_BLOCK (BLOCK_THREADS / 64)   // 16
#define VERTS_PER_WAVE 2                       // one pair per wave (lane halves)
// grid = 8192 / (16*2) = 256 blocks -> 1 block/CU, 4 waves/SIMD

typedef float f32x2 __attribute__((ext_vector_type(2)));

__device__ __forceinline__ float bcast(float x, int srclane) {
    return __uint_as_float(__builtin_amdgcn_readlane(__float_as_uint(x), (unsigned)srclane));
}

__global__ __launch_bounds__(BLOCK_THREADS, 4) void conv_surface_kernel(
    const int* __restrict__ nidx,     // (bs, V, N) int32
    const float* __restrict__ verts,  // (bs, V, 3) f32
    const float* __restrict__ dirs,   // (3, S*K)   f32
    float* __restrict__ out)          // (bs, V, K) f32
{
    const int lane = threadIdx.x & 63;
    const int wave = threadIdx.x >> 6;
    const int gw   = blockIdx.x * WAVES_PER_BLOCK + wave;  // global wave id
    const int v0   = gw * VERTS_PER_WAVE;                  // first vertex of pair

    // ---- issue ALL independent loads up front ----
    // dirs columns owned by this lane: m = s*64 + lane
    float a0[S_SUP], a1[S_SUP], a2[S_SUP];
#pragma unroll
    for (int s = 0; s < S_SUP; ++s) {
        const int m = s * K_OUT + lane;
        a0[s] = dirs[0 * SK + m];
        a1[s] = dirs[1 * SK + m];
        a2[s] = dirs[2 * SK + m];
    }

    // lane half h gathers vertex v0+h; lane&31 = neighbor index
    const int h  = lane >> 5;
    const int ln = lane & 31;
    const int vg = v0 + h;                 // vertex this half gathers for
    const int bbase = (vg >> 12) << 12;    // batch base (V=4096 = 2^12)

    const int j  = nidx[vg * N_NBR + ln];
    const float cx = verts[vg * 3 + 0];    // uniform-per-half -> cache broadcast
    const float cy = verts[vg * 3 + 1];
    const float cz = verts[vg * 3 + 2];

    const float gx = verts[(bbase + j) * 3 + 0];
    const float gy = verts[(bbase + j) * 3 + 1];
    const float gz = verts[(bbase + j) * 3 + 2];

    // ---- normalize direction columns (overlaps gather latency) ----
    f32x2 D0[S_SUP / 2], D1[S_SUP / 2], D2[S_SUP / 2];
#pragma unroll
    for (int p = 0; p < S_SUP / 2; ++p) {
        const int s0 = 2 * p, s1 = 2 * p + 1;
        const float i0 = 1.0f / fmaxf(sqrtf(a0[s0]*a0[s0] + a1[s0]*a1[s0] + a2[s0]*a2[s0]), EPS);
        const float i1 = 1.0f / fmaxf(sqrtf(a0[s1]*a0[s1] + a1[s1]*a1[s1] + a2[s1]*a2[s1]), EPS);
        D0[p] = (f32x2){a0[s0] * i0, a0[s1] * i1};
        D1[p] = (f32x2){a1[s0] * i0, a1[s1] * i1};
        D2[p] = (f32x2){a2[s0] * i0, a2[s1] * i1};
    }

    // ---- normalize neighbor diffs (all 64 lanes busy; 2 vertices at once) ----
    const float dx = gx - cx;
    const float dy = gy - cy;
    const float dz = gz - cz;
    const float inv = 1.0f / fmaxf(sqrtf(dx*dx + dy*dy + dz*dz), EPS);
    const float ndx = dx * inv;
    const float ndy = dy * inv;
    const float ndz = dz * inv;

    // ---- compute both vertices of the pair; broadcast via readlane ----
#pragma unroll
    for (int v = 0; v < VERTS_PER_WAVE; ++v) {
        f32x2 th[S_SUP / 2];
#pragma unroll
        for (int p = 0; p < S_SUP / 2; ++p) th[p] = (f32x2){0.0f, 0.0f};

        const int base = v * 32;   // lane half holding vertex v's neighbors
#pragma unroll 8
        for (int n = 0; n < N_NBR; ++n) {
            const float nx = bcast(ndx, base + n);
            const float ny = bcast(ndy, base + n);
            const float nz = bcast(ndz, base + n);
            const f32x2 vx = (f32x2){nx, nx};
            const f32x2 vy = (f32x2){ny, ny};
            const f32x2 vz = (f32x2){nz, nz};
#pragma unroll
            for (int p = 0; p < S_SUP / 2; ++p) {
                f32x2 t = vx * D0[p];
                t = t + vy * D1[p];                       // v_pk_fma_f32
                t = t + vz * D2[p];
                th[p] = __builtin_elementwise_max(th[p], t);  // v_pk_max_f32 (relu via 0-init)
            }
        }

        float acc = 0.0f;
#pragma unroll
        for (int p = 0; p < S_SUP / 2; ++p) acc += th[p].x + th[p].y;

        out[(v0 + v) * K_OUT + lane] = acc;   // coalesced 256B per wave
    }
}

extern "C" void kernel_launch(void* const* d_in, const int* in_sizes, int n_in,
                              void* d_out, int out_size, void* d_ws, size_t ws_size,
                              hipStream_t stream) {
    const int*   nidx  = (const int*)d_in[0];
    const float* verts = (const float*)d_in[1];
    const float* dirs  = (const float*)d_in[2];
    float*       out   = (float*)d_out;

    const int total_v = BS * V_DIM;                                   // 8192
    const int blocks  = total_v / (WAVES_PER_BLOCK * VERTS_PER_WAVE); // 256
    conv_surface_kernel<<<blocks, BLOCK_THREADS, 0, stream>>>(nidx, verts, dirs, out);
}

// Round 4
// 15.861 us; speedup vs baseline: 1.2039x; 1.2039x over previous
//
#include <hip/hip_runtime.h>

// Problem constants: bs=2, V=4096, N=32, S=8, K=64 (S*K=512)
#define BS 2
#define V_DIM 4096
#define N_NBR 32
#define S_SUP 8
#define K_OUT 64
#define SK (S_SUP * K_OUT)
#define WAVES_PER_BLOCK 4

typedef float f32x2 __attribute__((ext_vector_type(2)));
typedef float f32x4 __attribute__((ext_vector_type(4)));

__global__ __launch_bounds__(WAVES_PER_BLOCK * 64) void conv_surface_kernel(
    const int* __restrict__ nidx,     // (bs, V, N) int32
    const float* __restrict__ verts,  // (bs, V, 3) f32
    const float* __restrict__ dirs,   // (3, S*K)   f32
    float* __restrict__ out)          // (bs, V, K) f32
{
    const int lane = threadIdx.x & 63;
    const int wave = threadIdx.x >> 6;
    const int vi   = blockIdx.x * WAVES_PER_BLOCK + wave;   // in [0, BS*V)
    const int bbase = (vi >> 12) << 12;                     // batch base (V = 2^12)

    // Per-wave private LDS slice: [n] -> {ndx, ndy, ndz, pad}. No cross-wave
    // sharing => no __syncthreads needed (same-wave ds_write->ds_read is
    // ordered via lgkmcnt; compiler keeps aliasing LDS ops in order).
    __shared__ __align__(16) float snd[WAVES_PER_BLOCK][N_NBR][4];

    // ---- issue all independent loads up front ----
    float a0[S_SUP], a1[S_SUP], a2[S_SUP];
#pragma unroll
    for (int s = 0; s < S_SUP; ++s) {
        const int m = s * K_OUT + lane;
        a0[s] = dirs[0 * SK + m];
        a1[s] = dirs[1 * SK + m];
        a2[s] = dirs[2 * SK + m];
    }

    int j = 0;
    if (lane < N_NBR) j = nidx[vi * N_NBR + lane];
    const float cx = verts[vi * 3 + 0];   // wave-uniform -> cache broadcast
    const float cy = verts[vi * 3 + 1];
    const float cz = verts[vi * 3 + 2];

    if (lane < N_NBR) {
        const float dx = verts[(bbase + j) * 3 + 0] - cx;
        const float dy = verts[(bbase + j) * 3 + 1] - cy;
        const float dz = verts[(bbase + j) * 3 + 2] - cz;
        // 1/max(sqrt(d2),1e-12) == rsqrt(max(d2,1e-24)); rsqrt(1e-24)*0 = 0.
        const float inv = __frsqrt_rn(fmaxf(dx * dx + dy * dy + dz * dz, 1e-24f));
        f32x4 q = {dx * inv, dy * inv, dz * inv, 0.0f};
        *reinterpret_cast<f32x4*>(&snd[wave][lane][0]) = q;   // ds_write_b128
    }

    // ---- normalize direction columns (overlaps gather latency) ----
    f32x2 D0[S_SUP / 2], D1[S_SUP / 2], D2[S_SUP / 2];
#pragma unroll
    for (int p = 0; p < S_SUP / 2; ++p) {
        const int s0 = 2 * p, s1 = 2 * p + 1;
        const float i0 = __frsqrt_rn(fmaxf(a0[s0]*a0[s0] + a1[s0]*a1[s0] + a2[s0]*a2[s0], 1e-24f));
        const float i1 = __frsqrt_rn(fmaxf(a0[s1]*a0[s1] + a1[s1]*a1[s1] + a2[s1]*a2[s1], 1e-24f));
        D0[p] = (f32x2){a0[s0] * i0, a0[s1] * i1};
        D1[p] = (f32x2){a1[s0] * i0, a1[s1] * i1};
        D2[p] = (f32x2){a2[s0] * i0, a2[s1] * i1};
    }

    // relu + max over neighbors folds into max with 0 init.
    f32x2 th[S_SUP / 2];
#pragma unroll
    for (int p = 0; p < S_SUP / 2; ++p) th[p] = (f32x2){0.0f, 0.0f};

#pragma unroll
    for (int n = 0; n < N_NBR; ++n) {
        const f32x4 q = *reinterpret_cast<const f32x4*>(&snd[wave][n][0]); // ds_read_b128, broadcast
        const f32x2 vx = (f32x2){q.x, q.x};   // op_sel same-reg broadcast
        const f32x2 vy = (f32x2){q.y, q.y};
        const f32x2 vz = (f32x2){q.z, q.z};
#pragma unroll
        for (int p = 0; p < S_SUP / 2; ++p) {
            f32x2 t = vx * D0[p];
            t = t + vy * D1[p];                           // v_pk_fma_f32
            t = t + vz * D2[p];
            th[p] = __builtin_elementwise_max(th[p], t);  // v_pk_max_f32
        }
    }

    float acc = 0.0f;
#pragma unroll
    for (int p = 0; p < S_SUP / 2; ++p) acc += th[p].x + th[p].y;

    out[vi * K_OUT + lane] = acc;   // coalesced 256B per wave
}

extern "C" void kernel_launch(void* const* d_in, const int* in_sizes, int n_in,
                              void* d_out, int out_size, void* d_ws, size_t ws_size,
                              hipStream_t stream) {
    const int*   nidx  = (const int*)d_in[0];
    const float* verts = (const float*)d_in[1];
    const float* dirs  = (const float*)d_in[2];
    float*       out   = (float*)d_out;

    const int total_v = BS * V_DIM;                       // 8192
    const int blocks  = total_v / WAVES_PER_BLOCK;        // 2048
    conv_surface_kernel<<<blocks, WAVES_PER_BLOCK * 64, 0, stream>>>(nidx, verts, dirs, out);
}